// Round 3
// baseline (270.048 us; speedup 1.0000x reference)
//
#include <hip/hip_runtime.h>

// Problem constants: B=32 graphs, N=1024 nodes/graph, F=64, D=128, DEG=8
#define E_TOTAL 262144     // B*N*DEG
#define NGRAPH  32
#define EPG     8192       // edges per graph
#define EPS_BN  1e-5f
#define MB (1u << 20)
#define KB (1u << 10)

__device__ __forceinline__ float lrelu(float x){ return x > 0.f ? x : 0.2f * x; }

// XCD-aware block swizzle (locality-neutral in r1 but harmless).
__device__ __forceinline__ int xcd_swz(int b, int n){ return (b & 7) * (n >> 3) + (b >> 3); }

// In-kernel grid barrier for kernels whose grid is provably co-resident
// (gridDim <= guaranteed blocks/CU * 256). Counter must be pre-zeroed (mega1 does it).
// Release on arrive; relaxed poll; single acquire on exit (one L2 inv, not per-poll).
__device__ __forceinline__ void grid_bar(int* bar, int n){
  __syncthreads();
  if (threadIdx.x == 0){
    __hip_atomic_fetch_add(bar, 1, __ATOMIC_RELEASE, __HIP_MEMORY_SCOPE_AGENT);
    while (__hip_atomic_load(bar, __ATOMIC_RELAXED, __HIP_MEMORY_SCOPE_AGENT) < n)
      __builtin_amdgcn_s_sleep(8);
    (void)__hip_atomic_load(bar, __ATOMIC_ACQUIRE, __HIP_MEMORY_SCOPE_AGENT);
  }
  __syncthreads();
}

// exclusive scan of B = 256*Q LDS bins by 256 threads; writes cnt/row_start globals,
// leaves per-bin exclusive cursors in h. Caller must barrier before entry.
template<int Q>
__device__ __forceinline__ void scan_bins(int* h, int* cnt_g, int* rs_g, int B, int g,
                                          int ebase, int* wsum){
  int t = threadIdx.x, lane = t & 63, w = t >> 6;
  int c[Q]; int s = 0;
  #pragma unroll
  for (int i = 0; i < Q; ++i){ c[i] = h[t * Q + i]; s += c[i]; }
  int v = s;
  #pragma unroll
  for (int o = 1; o < 64; o <<= 1){ int u = __shfl_up(v, o); if (lane >= o) v += u; }
  if (lane == 63) wsum[w] = v;
  __syncthreads();
  if (t == 0){ int run = 0;
    #pragma unroll
    for (int i = 0; i < 4; ++i){ int x = wsum[i]; wsum[i] = run; run += x; } }
  __syncthreads();
  int run = v - s + wsum[w];
  #pragma unroll
  for (int i = 0; i < Q; ++i){
    cnt_g[g * B + t * Q + i] = c[i];
    rs_g [g * B + t * Q + i] = ebase + run;
    h[t * Q + i] = run;
    run += c[i];
  }
  __syncthreads();
}

// ---------------- mega1: CSR build (all 3 layers) CO-DISPATCHED with layer-1 GEMM -------
// blocks 0..95: CSR. role 0 (0-31): L1 hist+scan+scatter (no dedupe). role 1 (32-63):
// L2 pair-dedupe bitmap + hist/scan/scatter. role 2 (64-95): redo L2 dedupe + L3 dedupe
// + hist/scan/scatter. 256 thr, 32 edges/thread. Also zeroes bn sums + barrier counters.
// blocks 96..1119: layer-1 GEMM (1024 tiles of 32 rows), h = x0 @ W0, es/ed epilogue.
__global__ __launch_bounds__(256, 2)
void mega1(const float* __restrict__ x0, const float* __restrict__ W0,
           const float* __restrict__ a_s, const float* __restrict__ a_d,
           const int* __restrict__ src0, const int* __restrict__ dst0,
           float* __restrict__ C, float* __restrict__ es, float* __restrict__ ed,
           int* __restrict__ csr1, int* __restrict__ csr2, int* __restrict__ csr3,
           int* __restrict__ rs1, int* __restrict__ rs2, int* __restrict__ rs3,
           int* __restrict__ cnt1, int* __restrict__ cnt2, int* __restrict__ cnt3,
           float* __restrict__ sums_all, int* __restrict__ bars){
  __shared__ __align__(16) char smem[45072];   // union: csr 44KB / gemm 41KB
  __shared__ int wsum[4];
  int t = threadIdx.x;
  int raw = blockIdx.x;

  if (raw < 96){
    int* bm2 = (int*)smem;          // [8192] 32 KB
    int* bm3 = bm2 + 8192;          // [2048]  8 KB
    int* h   = bm3 + 2048;          // [1024]  4 KB
    int role = raw >> 5, g = raw & 31, ebase = g * EPG;
    if (raw == 0 && t < 48) bars[t] = 0;          // 3 barrier counters (64B apart)
    if (role == 0 && t < 24) sums_all[g * 24 + t] = 0.f;  // 768 bn-sum floats

    if (role == 0){
      // ---- L1: no dedupe, 1024 bins ----
      for (int i = t; i < 1024; i += 256) h[i] = 0;
      __syncthreads();
      for (int i = 0; i < 32; ++i){
        int e = ebase + i * 256 + t;
        int sv = src0[e], dv = dst0[e];
        if (sv != dv) atomicAdd(&h[dv & 1023], 1);
      }
      __syncthreads();
      scan_bins<4>(h, cnt1, rs1, 1024, g, ebase, wsum);
      for (int i = 0; i < 32; ++i){
        int e = ebase + i * 256 + t;
        int sv = src0[e], dv = dst0[e];
        if (sv != dv){
          int p = atomicAdd(&h[dv & 1023], 1);
          csr1[ebase + p] = sv;
        }
      }
    } else if (role == 1){
      // ---- L2: pair-dedupe (512x512 bitmap), 512 bins ----
      for (int i = t; i < 8192; i += 256) bm2[i] = 0;
      for (int i = t; i < 512; i += 256) h[i] = 0;
      __syncthreads();
      unsigned int k2m = 0;
      for (int i = 0; i < 32; ++i){
        int e = ebase + i * 256 + t;
        int sv = src0[e], dv = dst0[e];
        if (sv != dv){
          int s2 = (sv >> 1) & 511, d2 = (dv >> 1) & 511;
          if (s2 != d2){
            int key = (s2 << 9) | d2;
            unsigned int bit = 1u << (key & 31);
            unsigned int old = atomicOr((unsigned int*)&bm2[key >> 5], bit);
            if (!(old & bit)){ k2m |= 1u << i; atomicAdd(&h[d2], 1); }
          }
        }
      }
      __syncthreads();
      scan_bins<2>(h, cnt2, rs2, 512, g, ebase, wsum);
      for (int i = 0; i < 32; ++i){
        if ((k2m >> i) & 1u){
          int e = ebase + i * 256 + t;
          int sv = src0[e], dv = dst0[e];
          int p = atomicAdd(&h[(dv >> 1) & 511], 1);
          csr2[ebase + p] = sv >> 1;
        }
      }
    } else {
      // ---- L3: redo L2 dedupe (independent bitmap) then L3 dedupe, 256 bins ----
      for (int i = t; i < 8192; i += 256) bm2[i] = 0;
      for (int i = t; i < 2048; i += 256) bm3[i] = 0;
      for (int i = t; i < 256; i += 256) h[i] = 0;
      __syncthreads();
      unsigned int k3m = 0;
      for (int i = 0; i < 32; ++i){
        int e = ebase + i * 256 + t;
        int sv = src0[e], dv = dst0[e];
        if (sv != dv){
          int s2 = (sv >> 1) & 511, d2 = (dv >> 1) & 511;
          if (s2 != d2){
            int key = (s2 << 9) | d2;
            unsigned int bit = 1u << (key & 31);
            unsigned int old = atomicOr((unsigned int*)&bm2[key >> 5], bit);
            if (!(old & bit)){
              int s3 = (sv >> 2) & 255, d3 = (dv >> 2) & 255;
              if (s3 != d3){
                int key3 = (s3 << 8) | d3;
                unsigned int b3 = 1u << (key3 & 31);
                unsigned int o3 = atomicOr((unsigned int*)&bm3[key3 >> 5], b3);
                if (!(o3 & b3)){ k3m |= 1u << i; atomicAdd(&h[d3], 1); }
              }
            }
          }
        }
      }
      __syncthreads();
      scan_bins<1>(h, cnt3, rs3, 256, g, ebase, wsum);
      for (int i = 0; i < 32; ++i){
        if ((k3m >> i) & 1u){
          int e = ebase + i * 256 + t;
          int sv = src0[e], dv = dst0[e];
          int p = atomicAdd(&h[(dv >> 2) & 255], 1);
          csr3[ebase + p] = sv >> 2;
        }
      }
    }
    return;
  }

  // ---- layer-1 GEMM tile (K=64, no BN) ----
  float* Ws   = (float*)smem;       // [64*128] 32 KB
  float* As_t = Ws + 8192;          // [64*36]   9 KB
  int tile = xcd_swz(raw - 96, 1024);
  int row0 = tile * 32;
  int c2 = t & 63, rg = t >> 6;
  float2 acc[8];
  #pragma unroll
  for (int i = 0; i < 8; ++i){ acc[i].x = 0.f; acc[i].y = 0.f; }

  for (int i = t; i < 8192; i += 256) Ws[i] = W0[i];
  #pragma unroll
  for (int it = 0; it < 8; ++it){
    int i = it * 256 + t;
    int r = i >> 6, kk = i & 63;
    As_t[kk * 36 + r] = x0[(size_t)(row0 + r) * 64 + kk];
  }
  __syncthreads();
  #pragma unroll 8
  for (int kk = 0; kk < 64; ++kk){
    float2 w = *(float2*)&Ws[kk * 128 + c2 * 2];
    float4 a0 = *(float4*)&As_t[kk * 36 + rg * 8];
    float4 a1 = *(float4*)&As_t[kk * 36 + rg * 8 + 4];
    acc[0].x = fmaf(a0.x, w.x, acc[0].x); acc[0].y = fmaf(a0.x, w.y, acc[0].y);
    acc[1].x = fmaf(a0.y, w.x, acc[1].x); acc[1].y = fmaf(a0.y, w.y, acc[1].y);
    acc[2].x = fmaf(a0.z, w.x, acc[2].x); acc[2].y = fmaf(a0.z, w.y, acc[2].y);
    acc[3].x = fmaf(a0.w, w.x, acc[3].x); acc[3].y = fmaf(a0.w, w.y, acc[3].y);
    acc[4].x = fmaf(a1.x, w.x, acc[4].x); acc[4].y = fmaf(a1.x, w.y, acc[4].y);
    acc[5].x = fmaf(a1.y, w.x, acc[5].x); acc[5].y = fmaf(a1.y, w.y, acc[5].y);
    acc[6].x = fmaf(a1.z, w.x, acc[6].x); acc[6].y = fmaf(a1.z, w.y, acc[6].y);
    acc[7].x = fmaf(a1.w, w.x, acc[7].x); acc[7].y = fmaf(a1.w, w.y, acc[7].y);
  }
  float2 as2 = ((const float2*)a_s)[c2];
  float2 ad2 = ((const float2*)a_d)[c2];
  float2* C2 = (float2*)C;
  #pragma unroll
  for (int i = 0; i < 8; ++i){
    int r = row0 + rg * 8 + i;
    C2[(size_t)r * 64 + c2] = acc[i];
    float e1 = acc[i].x * as2.x + acc[i].y * as2.y;
    float e2 = acc[i].x * ad2.x + acc[i].y * ad2.y;
    #pragma unroll
    for (int o = 32; o; o >>= 1){ e1 += __shfl_xor(e1, o); e2 += __shfl_xor(e2, o); }
    if (c2 == 0){ es[r] = e1; ed[r] = e2; }
  }
}

// ---------------- GEMM (K=128) with fused BN-stats prologue -----------------------------
// All blocks compute the batch stats of A (the pooled X) with device atomics, meet at an
// in-kernel barrier (grid <= 512 <= guaranteed residency from __launch_bounds__(256,2)),
// then run C = bn(A) @ W with es/ed epilogue. Replaces the separate bn_stats dispatch.
__global__ __launch_bounds__(256, 2)
void gemm_attn128(const float* __restrict__ A, const float* __restrict__ W,
                  float* __restrict__ sums, float invM, int Mstats,
                  const float* __restrict__ a_s, const float* __restrict__ a_d,
                  float* __restrict__ C, float* __restrict__ es, float* __restrict__ ed,
                  int* __restrict__ bar){
  __shared__ float Ws[64 * 128];    // 32 KB
  __shared__ float As_t[64 * 36];   // 9 KB
  __shared__ float bnmu[128], bnrs[128];
  __shared__ float s1[256], s2[256];
  int t = threadIdx.x;

  // ---- fused bn_stats over all gridDim blocks ----
  {
    int c = t & 127, half = t >> 7;
    float a = 0.f, b = 0.f;
    for (int r = blockIdx.x * 2 + half; r < Mstats; r += 2 * gridDim.x){
      float v = A[(size_t)r * 128 + c];
      a += v; b += v * v;
    }
    s1[t] = a; s2[t] = b;
    __syncthreads();
    if (t < 128){
      atomicAdd(&sums[c],       s1[t] + s1[t + 128]);
      atomicAdd(&sums[128 + c], s2[t] + s2[t + 128]);
    }
    grid_bar(bar, gridDim.x);
    if (t < 128){
      float mu = sums[t] * invM;
      float var = sums[128 + t] * invM - mu * mu;
      bnmu[t] = mu; bnrs[t] = rsqrtf(var + EPS_BN);
    }
    __syncthreads();
  }

  int bid = xcd_swz(blockIdx.x, gridDim.x);
  int row0 = bid * 32;
  int c2 = t & 63, rg = t >> 6;
  float2 acc[8];
  #pragma unroll
  for (int i = 0; i < 8; ++i){ acc[i].x = 0.f; acc[i].y = 0.f; }

  for (int k0 = 0; k0 < 128; k0 += 64){
    __syncthreads();
    for (int i = t; i < 64 * 128; i += 256)
      Ws[i] = W[(size_t)(k0 + (i >> 7)) * 128 + (i & 127)];
    #pragma unroll
    for (int it = 0; it < 8; ++it){
      int i = it * 256 + t;
      int r = i >> 6, kk = i & 63;
      float v = A[(size_t)(row0 + r) * 128 + k0 + kk];
      v = (v - bnmu[k0 + kk]) * bnrs[k0 + kk];
      As_t[kk * 36 + r] = v;
    }
    __syncthreads();
    #pragma unroll 8
    for (int kk = 0; kk < 64; ++kk){
      float2 w = *(float2*)&Ws[kk * 128 + c2 * 2];
      float4 a0 = *(float4*)&As_t[kk * 36 + rg * 8];
      float4 a1 = *(float4*)&As_t[kk * 36 + rg * 8 + 4];
      acc[0].x = fmaf(a0.x, w.x, acc[0].x); acc[0].y = fmaf(a0.x, w.y, acc[0].y);
      acc[1].x = fmaf(a0.y, w.x, acc[1].x); acc[1].y = fmaf(a0.y, w.y, acc[1].y);
      acc[2].x = fmaf(a0.z, w.x, acc[2].x); acc[2].y = fmaf(a0.z, w.y, acc[2].y);
      acc[3].x = fmaf(a0.w, w.x, acc[3].x); acc[3].y = fmaf(a0.w, w.y, acc[3].y);
      acc[4].x = fmaf(a1.x, w.x, acc[4].x); acc[4].y = fmaf(a1.x, w.y, acc[4].y);
      acc[5].x = fmaf(a1.y, w.x, acc[5].x); acc[5].y = fmaf(a1.y, w.y, acc[5].y);
      acc[6].x = fmaf(a1.z, w.x, acc[6].x); acc[6].y = fmaf(a1.z, w.y, acc[6].y);
      acc[7].x = fmaf(a1.w, w.x, acc[7].x); acc[7].y = fmaf(a1.w, w.y, acc[7].y);
    }
  }
  float2 as2 = ((const float2*)a_s)[c2];
  float2 ad2 = ((const float2*)a_d)[c2];
  float2* C2 = (float2*)C;
  #pragma unroll
  for (int i = 0; i < 8; ++i){
    int r = row0 + rg * 8 + i;
    C2[(size_t)r * 64 + c2] = acc[i];
    float e1 = acc[i].x * as2.x + acc[i].y * as2.y;
    float e2 = acc[i].x * ad2.x + acc[i].y * ad2.y;
    #pragma unroll
    for (int o = 32; o; o >>= 1){ e1 += __shfl_xor(e1, o); e2 += __shfl_xor(e2, o); }
    if (c2 == 0){ es[r] = e1; ed[r] = e2; }
  }
}

// ---------------- GAT softmax-aggregate + bias + ReLU + pairwise max-pool ----------------
// one wave per dst node; block 256 -> nodes 4b..4b+3 = pool pairs; writes M/2 pooled rows.
// Phase A caches the first 64 (src, logit) per lane so phase B skips the re-gather.
__global__ void gat_pool(const float* __restrict__ h, const float* __restrict__ es,
                         const float* __restrict__ ed, const int* __restrict__ csr_src,
                         const int* __restrict__ row_start, const int* __restrict__ row_cnt,
                         const float* __restrict__ bias, float* __restrict__ xout, int M){
  __shared__ float2 osh[4][64];
  int lane = threadIdx.x & 63;
  int wave = threadIdx.x >> 6;
  int bid = xcd_swz(blockIdx.x, gridDim.x);
  int n = bid * 4 + wave;
  int start = row_start[n];
  int cnt   = row_cnt[n];
  float edn = ed[n];
  float selfl = lrelu(es[n] + edn);

  float m_l = -1e30f, d_l = 0.f;
  int   s_c = 0; float l_c = 0.f;
  for (int c0 = 0; c0 < cnt; c0 += 64){
    int j = c0 + lane;
    if (j < cnt){
      int s = csr_src[start + j];
      float l = lrelu(es[s] + edn);
      if (c0 == 0){ s_c = s; l_c = l; }
      float mn = fmaxf(m_l, l);
      d_l = d_l * __expf(m_l - mn) + __expf(l - mn);
      m_l = mn;
    }
  }
  #pragma unroll
  for (int o = 32; o; o >>= 1){
    float m2 = __shfl_xor(m_l, o), d2 = __shfl_xor(d_l, o);
    float mn = fmaxf(m_l, m2);
    d_l = d_l * __expf(m_l - mn) + d2 * __expf(m2 - mn);
    m_l = mn;
  }
  float mf  = fmaxf(m_l, selfl);
  float den = d_l * __expf(m_l - mf) + __expf(selfl - mf);

  const float2* h2 = (const float2*)h;
  float sw = __expf(selfl - mf);
  float2 hv = h2[(size_t)n * 64 + lane];
  float2 acc; acc.x = sw * hv.x; acc.y = sw * hv.y;
  for (int c0 = 0; c0 < cnt; c0 += 64){
    int j = c0 + lane;
    int s_j; float w_j;
    if (c0 == 0){
      s_j = s_c;
      w_j = (lane < cnt) ? __expf(l_c - mf) : 0.f;
    } else {
      s_j = 0; w_j = 0.f;
      if (j < cnt){
        s_j = csr_src[start + j];
        w_j = __expf(lrelu(es[s_j] + edn) - mf);
      }
    }
    int rem = min(64, cnt - c0);
    int k = 0;
    for (; k + 8 <= rem; k += 8){
      int ss[8]; float ww[8]; float2 hh[8];
      #pragma unroll
      for (int i = 0; i < 8; ++i){ ss[i] = __shfl(s_j, k + i); ww[i] = __shfl(w_j, k + i); }
      #pragma unroll
      for (int i = 0; i < 8; ++i){ hh[i] = h2[(size_t)ss[i] * 64 + lane]; }
      #pragma unroll
      for (int i = 0; i < 8; ++i){
        acc.x = fmaf(ww[i], hh[i].x, acc.x);
        acc.y = fmaf(ww[i], hh[i].y, acc.y);
      }
    }
    for (; k < rem; ++k){
      int s = __shfl(s_j, k); float w = __shfl(w_j, k);
      float2 hh = h2[(size_t)s * 64 + lane];
      acc.x = fmaf(w, hh.x, acc.x);
      acc.y = fmaf(w, hh.y, acc.y);
    }
  }
  float inv = 1.f / den;
  float2 bv = ((const float2*)bias)[lane];
  float2 o2;
  o2.x = fmaxf(acc.x * inv + bv.x, 0.f);
  o2.y = fmaxf(acc.y * inv + bv.y, 0.f);
  osh[wave][lane] = o2;
  __syncthreads();
  if (wave < 2){
    float2 a = osh[2 * wave][lane], b = osh[2 * wave + 1][lane];
    float2 p; p.x = fmaxf(a.x, b.x); p.y = fmaxf(a.y, b.y);
    ((float2*)xout)[(size_t)(bid * 2 + wave) * 64 + lane] = p;
  }
}

// ---------------- final: BN stats + normalize in one kernel (barrier-fused) --------------
__global__ __launch_bounds__(256)
void bn_final(const float* __restrict__ x, float* __restrict__ sums,
              float* __restrict__ out, int Mrows, int* __restrict__ bar){
  __shared__ float s1[256], s2[256];
  __shared__ float mu_s[128], rs_s[128];
  int t = threadIdx.x;
  int c = t & 127, half = t >> 7;
  float a = 0.f, b = 0.f;
  for (int r = blockIdx.x * 2 + half; r < Mrows; r += 2 * gridDim.x){
    float v = x[(size_t)r * 128 + c];
    a += v; b += v * v;
  }
  s1[t] = a; s2[t] = b;
  __syncthreads();
  if (t < 128){
    atomicAdd(&sums[c],       s1[t] + s1[t + 128]);
    atomicAdd(&sums[128 + c], s2[t] + s2[t + 128]);
  }
  grid_bar(bar, gridDim.x);
  if (t < 128){
    float mu = sums[t] / (float)Mrows;
    float var = sums[128 + t] / (float)Mrows - mu * mu;
    mu_s[t] = mu; rs_s[t] = rsqrtf(var + EPS_BN);
  }
  __syncthreads();
  int per = (Mrows * 128) / gridDim.x;
  int base = blockIdx.x * per;
  for (int i = t; i < per; i += 256){
    int e = base + i;
    int ch = e & 127;
    out[e] = (x[e] - mu_s[ch]) * rs_s[ch];
  }
}

extern "C" void kernel_launch(void* const* d_in, const int* in_sizes, int n_in,
                              void* d_out, int out_size, void* d_ws, size_t ws_size,
                              hipStream_t stream){
  const float* x0   = (const float*)d_in[0];
  const float* W0   = (const float*)d_in[1];
  const float* W1   = (const float*)d_in[2];
  const float* W2   = (const float*)d_in[3];
  const float* attS = (const float*)d_in[4];
  const float* attD = (const float*)d_in[5];
  const float* bias = (const float*)d_in[6];
  const int*   src0 = (const int*)d_in[7];
  const int*   dst0 = src0 + E_TOTAL;
  float* out = (float*)d_out;                  // (32, 16384) f32

  char* ws = (char*)d_ws;
  float* Hbuf   = (float*)(ws);                        // 16 MB
  float* Xbuf   = (float*)(ws + 16 * MB);              //  8 MB (pooled)
  int*   csr1   = (int*)  (ws + 24 * MB);              //  1 MB
  int*   csr2   = (int*)  (ws + 25 * MB);              //  1 MB
  int*   csr3   = (int*)  (ws + 26 * MB);              //  1 MB
  float* es     = (float*)(ws + 27 * MB);              // 128 KB
  float* ed     = (float*)(ws + 27 * MB + 128 * KB);   // 128 KB
  int*   rs1    = (int*)  (ws + 27 * MB + 256 * KB);   // 128 KB
  int*   rs2    = (int*)  (ws + 27 * MB + 384 * KB);   //  64 KB
  int*   rs3    = (int*)  (ws + 27 * MB + 448 * KB);   //  32 KB
  int*   cnt1   = (int*)  (ws + 27 * MB + 480 * KB);   // 128 KB
  int*   cnt2   = (int*)  (ws + 27 * MB + 608 * KB);   //  64 KB
  int*   cnt3   = (int*)  (ws + 27 * MB + 672 * KB);   //  32 KB
  float* sums   = (float*)(ws + 27 * MB + 704 * KB);   // 768 floats (3 layers x 256)
  int*   bars   = (int*)  (ws + 27 * MB + 708 * KB);   // 48 ints (3 counters, 64B apart)
  float* sums0 = sums, *sums1 = sums + 256, *sums2 = sums + 512;

  // ---- CSR (all 3 layers) co-dispatched with layer-1 GEMM; zeroes sums + bars ----
  mega1<<<1120, 256, 0, stream>>>(x0, W0, attS, attD, src0, dst0, Hbuf, es, ed,
                                  csr1, csr2, csr3, rs1, rs2, rs3, cnt1, cnt2, cnt3,
                                  sums, bars);

  // ---- layer 1 aggregate ----
  gat_pool<<<8192, 256, 0, stream>>>(Hbuf, es, ed, csr1, rs1, cnt1, bias, Xbuf, 32768);

  // ---- layer 2: stats(X) fused into GEMM ----
  gemm_attn128<<<512, 256, 0, stream>>>(Xbuf, W1, sums0, 1.f / 16384.f, 16384,
                                        attS + 128, attD + 128, Hbuf, es, ed, &bars[0]);
  gat_pool<<<4096, 256, 0, stream>>>(Hbuf, es, ed, csr2, rs2, cnt2, bias + 128, Xbuf, 16384);

  // ---- layer 3 ----
  gemm_attn128<<<256, 256, 0, stream>>>(Xbuf, W2, sums1, 1.f / 8192.f, 8192,
                                        attS + 256, attD + 256, Hbuf, es, ed, &bars[16]);
  gat_pool<<<2048, 256, 0, stream>>>(Hbuf, es, ed, csr3, rs3, cnt3, bias + 256, Xbuf, 8192);

  // ---- final BN stats + normalize ----
  bn_final<<<512, 256, 0, stream>>>(Xbuf, sums2, out, 4096, &bars[32]);
}

// Round 4
// 227.439 us; speedup vs baseline: 1.1873x; 1.1873x over previous
//
#include <hip/hip_runtime.h>

// Problem constants: B=32 graphs, N=1024 nodes/graph, F=64, D=128, DEG=8
#define E_TOTAL 262144     // B*N*DEG
#define NGRAPH  32
#define EPG     8192       // edges per graph
#define EPS_BN  1e-5f
#define MB (1u << 20)
#define KB (1u << 10)

__device__ __forceinline__ float lrelu(float x){ return x > 0.f ? x : 0.2f * x; }

// XCD-aware block swizzle (locality-neutral measured, harmless).
__device__ __forceinline__ int xcd_swz(int b, int n){ return (b & 7) * (n >> 3) + (b >> 3); }

// exclusive scan of B = 256*Q LDS bins by 256 threads; writes cnt/row_start globals,
// leaves per-bin exclusive cursors in h. Caller must barrier before entry.
template<int Q>
__device__ __forceinline__ void scan_bins(int* h, int* cnt_g, int* rs_g, int B, int g,
                                          int ebase, int* wsum){
  int t = threadIdx.x, lane = t & 63, w = t >> 6;
  int c[Q]; int s = 0;
  #pragma unroll
  for (int i = 0; i < Q; ++i){ c[i] = h[t * Q + i]; s += c[i]; }
  int v = s;
  #pragma unroll
  for (int o = 1; o < 64; o <<= 1){ int u = __shfl_up(v, o); if (lane >= o) v += u; }
  if (lane == 63) wsum[w] = v;
  __syncthreads();
  if (t == 0){ int run = 0;
    #pragma unroll
    for (int i = 0; i < 4; ++i){ int x = wsum[i]; wsum[i] = run; run += x; } }
  __syncthreads();
  int run = v - s + wsum[w];
  #pragma unroll
  for (int i = 0; i < Q; ++i){
    cnt_g[g * B + t * Q + i] = c[i];
    rs_g [g * B + t * Q + i] = ebase + run;
    h[t * Q + i] = run;
    run += c[i];
  }
  __syncthreads();
}

// ---------------- mega1: CSR build (all 3 layers) CO-DISPATCHED with layer-1 GEMM -------
// blocks 0..95: CSR. role 0 (0-31): L1 hist+scan+scatter (no dedupe). role 1 (32-63):
// L2 pair-dedupe bitmap + hist/scan/scatter. role 2 (64-95): redo L2 dedupe + L3 dedupe
// + hist/scan/scatter. 256 thr, 32 edges/thread. Role 0 also zeroes the bn-sum floats.
// blocks 96..1119: layer-1 GEMM (1024 tiles of 32 rows), h = x0 @ W0, es/ed epilogue.
// NOTE (r3 post-mortem): NO in-kernel grid barriers anywhere — a device-scope barrier
// measured ~45 us on this chip (cross-XCD arrival serialization + acquire invalidate),
// 4x the cost of a kernel-launch boundary. Launch boundaries are the sync primitive.
__global__ __launch_bounds__(256, 2)
void mega1(const float* __restrict__ x0, const float* __restrict__ W0,
           const float* __restrict__ a_s, const float* __restrict__ a_d,
           const int* __restrict__ src0, const int* __restrict__ dst0,
           float* __restrict__ C, float* __restrict__ es, float* __restrict__ ed,
           int* __restrict__ csr1, int* __restrict__ csr2, int* __restrict__ csr3,
           int* __restrict__ rs1, int* __restrict__ rs2, int* __restrict__ rs3,
           int* __restrict__ cnt1, int* __restrict__ cnt2, int* __restrict__ cnt3,
           float* __restrict__ sums_all){
  __shared__ __align__(16) char smem[45072];   // union: csr 44KB / gemm 41KB
  __shared__ int wsum[4];
  int t = threadIdx.x;
  int raw = blockIdx.x;

  if (raw < 96){
    int* bm2 = (int*)smem;          // [8192] 32 KB
    int* bm3 = bm2 + 8192;          // [2048]  8 KB
    int* h   = bm3 + 2048;          // [1024]  4 KB
    int role = raw >> 5, g = raw & 31, ebase = g * EPG;
    if (role == 0 && t < 24) sums_all[g * 24 + t] = 0.f;  // 768 bn-sum floats

    if (role == 0){
      // ---- L1: no dedupe, 1024 bins ----
      for (int i = t; i < 1024; i += 256) h[i] = 0;
      __syncthreads();
      for (int i = 0; i < 32; ++i){
        int e = ebase + i * 256 + t;
        int sv = src0[e], dv = dst0[e];
        if (sv != dv) atomicAdd(&h[dv & 1023], 1);
      }
      __syncthreads();
      scan_bins<4>(h, cnt1, rs1, 1024, g, ebase, wsum);
      for (int i = 0; i < 32; ++i){
        int e = ebase + i * 256 + t;
        int sv = src0[e], dv = dst0[e];
        if (sv != dv){
          int p = atomicAdd(&h[dv & 1023], 1);
          csr1[ebase + p] = sv;
        }
      }
    } else if (role == 1){
      // ---- L2: pair-dedupe (512x512 bitmap), 512 bins ----
      for (int i = t; i < 8192; i += 256) bm2[i] = 0;
      for (int i = t; i < 512; i += 256) h[i] = 0;
      __syncthreads();
      unsigned int k2m = 0;
      for (int i = 0; i < 32; ++i){
        int e = ebase + i * 256 + t;
        int sv = src0[e], dv = dst0[e];
        if (sv != dv){
          int s2 = (sv >> 1) & 511, d2 = (dv >> 1) & 511;
          if (s2 != d2){
            int key = (s2 << 9) | d2;
            unsigned int bit = 1u << (key & 31);
            unsigned int old = atomicOr((unsigned int*)&bm2[key >> 5], bit);
            if (!(old & bit)){ k2m |= 1u << i; atomicAdd(&h[d2], 1); }
          }
        }
      }
      __syncthreads();
      scan_bins<2>(h, cnt2, rs2, 512, g, ebase, wsum);
      for (int i = 0; i < 32; ++i){
        if ((k2m >> i) & 1u){
          int e = ebase + i * 256 + t;
          int sv = src0[e], dv = dst0[e];
          int p = atomicAdd(&h[(dv >> 1) & 511], 1);
          csr2[ebase + p] = sv >> 1;
        }
      }
    } else {
      // ---- L3: redo L2 dedupe (independent bitmap) then L3 dedupe, 256 bins ----
      for (int i = t; i < 8192; i += 256) bm2[i] = 0;
      for (int i = t; i < 2048; i += 256) bm3[i] = 0;
      for (int i = t; i < 256; i += 256) h[i] = 0;
      __syncthreads();
      unsigned int k3m = 0;
      for (int i = 0; i < 32; ++i){
        int e = ebase + i * 256 + t;
        int sv = src0[e], dv = dst0[e];
        if (sv != dv){
          int s2 = (sv >> 1) & 511, d2 = (dv >> 1) & 511;
          if (s2 != d2){
            int key = (s2 << 9) | d2;
            unsigned int bit = 1u << (key & 31);
            unsigned int old = atomicOr((unsigned int*)&bm2[key >> 5], bit);
            if (!(old & bit)){
              int s3 = (sv >> 2) & 255, d3 = (dv >> 2) & 255;
              if (s3 != d3){
                int key3 = (s3 << 8) | d3;
                unsigned int b3 = 1u << (key3 & 31);
                unsigned int o3 = atomicOr((unsigned int*)&bm3[key3 >> 5], b3);
                if (!(o3 & b3)){ k3m |= 1u << i; atomicAdd(&h[d3], 1); }
              }
            }
          }
        }
      }
      __syncthreads();
      scan_bins<1>(h, cnt3, rs3, 256, g, ebase, wsum);
      for (int i = 0; i < 32; ++i){
        if ((k3m >> i) & 1u){
          int e = ebase + i * 256 + t;
          int sv = src0[e], dv = dst0[e];
          int p = atomicAdd(&h[(dv >> 2) & 255], 1);
          csr3[ebase + p] = sv >> 2;
        }
      }
    }
    return;
  }

  // ---- layer-1 GEMM tile (K=64, no BN) ----
  float* Ws   = (float*)smem;       // [64*128] 32 KB
  float* As_t = Ws + 8192;          // [64*36]   9 KB
  int tile = xcd_swz(raw - 96, 1024);
  int row0 = tile * 32;
  int c2 = t & 63, rg = t >> 6;
  float2 acc[8];
  #pragma unroll
  for (int i = 0; i < 8; ++i){ acc[i].x = 0.f; acc[i].y = 0.f; }

  for (int i = t; i < 8192; i += 256) Ws[i] = W0[i];
  #pragma unroll
  for (int it = 0; it < 8; ++it){
    int i = it * 256 + t;
    int r = i >> 6, kk = i & 63;
    As_t[kk * 36 + r] = x0[(size_t)(row0 + r) * 64 + kk];
  }
  __syncthreads();
  #pragma unroll 8
  for (int kk = 0; kk < 64; ++kk){
    float2 w = *(float2*)&Ws[kk * 128 + c2 * 2];
    float4 a0 = *(float4*)&As_t[kk * 36 + rg * 8];
    float4 a1 = *(float4*)&As_t[kk * 36 + rg * 8 + 4];
    acc[0].x = fmaf(a0.x, w.x, acc[0].x); acc[0].y = fmaf(a0.x, w.y, acc[0].y);
    acc[1].x = fmaf(a0.y, w.x, acc[1].x); acc[1].y = fmaf(a0.y, w.y, acc[1].y);
    acc[2].x = fmaf(a0.z, w.x, acc[2].x); acc[2].y = fmaf(a0.z, w.y, acc[2].y);
    acc[3].x = fmaf(a0.w, w.x, acc[3].x); acc[3].y = fmaf(a0.w, w.y, acc[3].y);
    acc[4].x = fmaf(a1.x, w.x, acc[4].x); acc[4].y = fmaf(a1.x, w.y, acc[4].y);
    acc[5].x = fmaf(a1.y, w.x, acc[5].x); acc[5].y = fmaf(a1.y, w.y, acc[5].y);
    acc[6].x = fmaf(a1.z, w.x, acc[6].x); acc[6].y = fmaf(a1.z, w.y, acc[6].y);
    acc[7].x = fmaf(a1.w, w.x, acc[7].x); acc[7].y = fmaf(a1.w, w.y, acc[7].y);
  }
  float2 as2 = ((const float2*)a_s)[c2];
  float2 ad2 = ((const float2*)a_d)[c2];
  float2* C2 = (float2*)C;
  #pragma unroll
  for (int i = 0; i < 8; ++i){
    int r = row0 + rg * 8 + i;
    C2[(size_t)r * 64 + c2] = acc[i];
    float e1 = acc[i].x * as2.x + acc[i].y * as2.y;
    float e2 = acc[i].x * ad2.x + acc[i].y * ad2.y;
    #pragma unroll
    for (int o = 32; o; o >>= 1){ e1 += __shfl_xor(e1, o); e2 += __shfl_xor(e2, o); }
    if (c2 == 0){ es[r] = e1; ed[r] = e2; }
  }
}

// ---------------- GEMM (K=128) + attention terms, BN via precomputed sums ---------------
__global__ __launch_bounds__(256)
void gemm_attn128(const float* __restrict__ A, const float* __restrict__ W,
                  const float* __restrict__ bnsums, float invM,
                  const float* __restrict__ a_s, const float* __restrict__ a_d,
                  float* __restrict__ C, float* __restrict__ es, float* __restrict__ ed){
  __shared__ float Ws[64 * 128];    // 32 KB
  __shared__ float As_t[64 * 36];   // 9 KB
  __shared__ float bnmu[128], bnrs[128];
  int t = threadIdx.x;
  if (t < 128){
    float mu = bnsums[t] * invM;
    float var = bnsums[128 + t] * invM - mu * mu;
    bnmu[t] = mu; bnrs[t] = rsqrtf(var + EPS_BN);
  }
  int bid = xcd_swz(blockIdx.x, gridDim.x);
  int row0 = bid * 32;
  int c2 = t & 63, rg = t >> 6;
  float2 acc[8];
  #pragma unroll
  for (int i = 0; i < 8; ++i){ acc[i].x = 0.f; acc[i].y = 0.f; }

  for (int k0 = 0; k0 < 128; k0 += 64){
    __syncthreads();
    for (int i = t; i < 64 * 128; i += 256)
      Ws[i] = W[(size_t)(k0 + (i >> 7)) * 128 + (i & 127)];
    #pragma unroll
    for (int it = 0; it < 8; ++it){
      int i = it * 256 + t;
      int r = i >> 6, kk = i & 63;
      float v = A[(size_t)(row0 + r) * 128 + k0 + kk];
      v = (v - bnmu[k0 + kk]) * bnrs[k0 + kk];
      As_t[kk * 36 + r] = v;
    }
    __syncthreads();
    #pragma unroll 8
    for (int kk = 0; kk < 64; ++kk){
      float2 w = *(float2*)&Ws[kk * 128 + c2 * 2];
      float4 a0 = *(float4*)&As_t[kk * 36 + rg * 8];
      float4 a1 = *(float4*)&As_t[kk * 36 + rg * 8 + 4];
      acc[0].x = fmaf(a0.x, w.x, acc[0].x); acc[0].y = fmaf(a0.x, w.y, acc[0].y);
      acc[1].x = fmaf(a0.y, w.x, acc[1].x); acc[1].y = fmaf(a0.y, w.y, acc[1].y);
      acc[2].x = fmaf(a0.z, w.x, acc[2].x); acc[2].y = fmaf(a0.z, w.y, acc[2].y);
      acc[3].x = fmaf(a0.w, w.x, acc[3].x); acc[3].y = fmaf(a0.w, w.y, acc[3].y);
      acc[4].x = fmaf(a1.x, w.x, acc[4].x); acc[4].y = fmaf(a1.x, w.y, acc[4].y);
      acc[5].x = fmaf(a1.y, w.x, acc[5].x); acc[5].y = fmaf(a1.y, w.y, acc[5].y);
      acc[6].x = fmaf(a1.z, w.x, acc[6].x); acc[6].y = fmaf(a1.z, w.y, acc[6].y);
      acc[7].x = fmaf(a1.w, w.x, acc[7].x); acc[7].y = fmaf(a1.w, w.y, acc[7].y);
    }
  }
  float2 as2 = ((const float2*)a_s)[c2];
  float2 ad2 = ((const float2*)a_d)[c2];
  float2* C2 = (float2*)C;
  #pragma unroll
  for (int i = 0; i < 8; ++i){
    int r = row0 + rg * 8 + i;
    C2[(size_t)r * 64 + c2] = acc[i];
    float e1 = acc[i].x * as2.x + acc[i].y * as2.y;
    float e2 = acc[i].x * ad2.x + acc[i].y * ad2.y;
    #pragma unroll
    for (int o = 32; o; o >>= 1){ e1 += __shfl_xor(e1, o); e2 += __shfl_xor(e2, o); }
    if (c2 == 0){ es[r] = e1; ed[r] = e2; }
  }
}

// ---------------- GAT softmax-aggregate + bias + ReLU + pairwise max-pool ----------------
// one wave per dst node; block 256 -> nodes 4b..4b+3 = pool pairs; writes M/2 pooled rows.
// Phase A caches the first 64 (src, logit) per lane so phase B skips the re-gather.
__global__ void gat_pool(const float* __restrict__ h, const float* __restrict__ es,
                         const float* __restrict__ ed, const int* __restrict__ csr_src,
                         const int* __restrict__ row_start, const int* __restrict__ row_cnt,
                         const float* __restrict__ bias, float* __restrict__ xout, int M){
  __shared__ float2 osh[4][64];
  int lane = threadIdx.x & 63;
  int wave = threadIdx.x >> 6;
  int bid = xcd_swz(blockIdx.x, gridDim.x);
  int n = bid * 4 + wave;
  int start = row_start[n];
  int cnt   = row_cnt[n];
  float edn = ed[n];
  float selfl = lrelu(es[n] + edn);

  float m_l = -1e30f, d_l = 0.f;
  int   s_c = 0; float l_c = 0.f;
  for (int c0 = 0; c0 < cnt; c0 += 64){
    int j = c0 + lane;
    if (j < cnt){
      int s = csr_src[start + j];
      float l = lrelu(es[s] + edn);
      if (c0 == 0){ s_c = s; l_c = l; }
      float mn = fmaxf(m_l, l);
      d_l = d_l * __expf(m_l - mn) + __expf(l - mn);
      m_l = mn;
    }
  }
  #pragma unroll
  for (int o = 32; o; o >>= 1){
    float m2 = __shfl_xor(m_l, o), d2 = __shfl_xor(d_l, o);
    float mn = fmaxf(m_l, m2);
    d_l = d_l * __expf(m_l - mn) + d2 * __expf(m2 - mn);
    m_l = mn;
  }
  float mf  = fmaxf(m_l, selfl);
  float den = d_l * __expf(m_l - mf) + __expf(selfl - mf);

  const float2* h2 = (const float2*)h;
  float sw = __expf(selfl - mf);
  float2 hv = h2[(size_t)n * 64 + lane];
  float2 acc; acc.x = sw * hv.x; acc.y = sw * hv.y;
  for (int c0 = 0; c0 < cnt; c0 += 64){
    int j = c0 + lane;
    int s_j; float w_j;
    if (c0 == 0){
      s_j = s_c;
      w_j = (lane < cnt) ? __expf(l_c - mf) : 0.f;
    } else {
      s_j = 0; w_j = 0.f;
      if (j < cnt){
        s_j = csr_src[start + j];
        w_j = __expf(lrelu(es[s_j] + edn) - mf);
      }
    }
    int rem = min(64, cnt - c0);
    int k = 0;
    for (; k + 8 <= rem; k += 8){
      int ss[8]; float ww[8]; float2 hh[8];
      #pragma unroll
      for (int i = 0; i < 8; ++i){ ss[i] = __shfl(s_j, k + i); ww[i] = __shfl(w_j, k + i); }
      #pragma unroll
      for (int i = 0; i < 8; ++i){ hh[i] = h2[(size_t)ss[i] * 64 + lane]; }
      #pragma unroll
      for (int i = 0; i < 8; ++i){
        acc.x = fmaf(ww[i], hh[i].x, acc.x);
        acc.y = fmaf(ww[i], hh[i].y, acc.y);
      }
    }
    for (; k < rem; ++k){
      int s = __shfl(s_j, k); float w = __shfl(w_j, k);
      float2 hh = h2[(size_t)s * 64 + lane];
      acc.x = fmaf(w, hh.x, acc.x);
      acc.y = fmaf(w, hh.y, acc.y);
    }
  }
  float inv = 1.f / den;
  float2 bv = ((const float2*)bias)[lane];
  float2 o2;
  o2.x = fmaxf(acc.x * inv + bv.x, 0.f);
  o2.y = fmaxf(acc.y * inv + bv.y, 0.f);
  osh[wave][lane] = o2;
  __syncthreads();
  if (wave < 2){
    float2 a = osh[2 * wave][lane], b = osh[2 * wave + 1][lane];
    float2 p; p.x = fmaxf(a.x, b.x); p.y = fmaxf(a.y, b.y);
    ((float2*)xout)[(size_t)(bid * 2 + wave) * 64 + lane] = p;
  }
}

// ---------------- BN stats over pooled X (sums zeroed by mega1) --------------------------
__global__ void bn_stats(const float* __restrict__ x, float* __restrict__ sums, int M){
  __shared__ float s1[256], s2[256];
  int c = threadIdx.x & 127, half = threadIdx.x >> 7;
  float a = 0.f, b = 0.f;
  for (int r = blockIdx.x * 2 + half; r < M; r += 256){
    float v = x[(size_t)r * 128 + c];
    a += v; b += v * v;
  }
  s1[threadIdx.x] = a; s2[threadIdx.x] = b;
  __syncthreads();
  if (threadIdx.x < 128){
    atomicAdd(&sums[c],       s1[threadIdx.x] + s1[threadIdx.x + 128]);
    atomicAdd(&sums[128 + c], s2[threadIdx.x] + s2[threadIdx.x + 128]);
  }
}

// ---------------- final BatchNorm apply ----------------
__global__ void bn_norm(const float* __restrict__ in, const float* __restrict__ sums,
                        float* __restrict__ out, int M){
  int idx = blockIdx.x * blockDim.x + threadIdx.x;
  if (idx >= M * 128) return;
  int c = idx & 127;
  float mu  = sums[c] / (float)M;
  float var = sums[128 + c] / (float)M - mu * mu;
  out[idx] = (in[idx] - mu) * rsqrtf(var + EPS_BN);
}

extern "C" void kernel_launch(void* const* d_in, const int* in_sizes, int n_in,
                              void* d_out, int out_size, void* d_ws, size_t ws_size,
                              hipStream_t stream){
  const float* x0   = (const float*)d_in[0];
  const float* W0   = (const float*)d_in[1];
  const float* W1   = (const float*)d_in[2];
  const float* W2   = (const float*)d_in[3];
  const float* attS = (const float*)d_in[4];
  const float* attD = (const float*)d_in[5];
  const float* bias = (const float*)d_in[6];
  const int*   src0 = (const int*)d_in[7];
  const int*   dst0 = src0 + E_TOTAL;
  float* out = (float*)d_out;                  // (32, 16384) f32

  char* ws = (char*)d_ws;
  float* Hbuf   = (float*)(ws);                        // 16 MB
  float* Xbuf   = (float*)(ws + 16 * MB);              //  8 MB (pooled)
  int*   csr1   = (int*)  (ws + 24 * MB);              //  1 MB
  int*   csr2   = (int*)  (ws + 25 * MB);              //  1 MB
  int*   csr3   = (int*)  (ws + 26 * MB);              //  1 MB
  float* es     = (float*)(ws + 27 * MB);              // 128 KB
  float* ed     = (float*)(ws + 27 * MB + 128 * KB);   // 128 KB
  int*   rs1    = (int*)  (ws + 27 * MB + 256 * KB);   // 128 KB
  int*   rs2    = (int*)  (ws + 27 * MB + 384 * KB);   //  64 KB
  int*   rs3    = (int*)  (ws + 27 * MB + 448 * KB);   //  32 KB
  int*   cnt1   = (int*)  (ws + 27 * MB + 480 * KB);   // 128 KB
  int*   cnt2   = (int*)  (ws + 27 * MB + 608 * KB);   //  64 KB
  int*   cnt3   = (int*)  (ws + 27 * MB + 672 * KB);   //  32 KB
  float* sums   = (float*)(ws + 27 * MB + 704 * KB);   // 768 floats (3 layers x 256)
  float* sums0 = sums, *sums1 = sums + 256, *sums2 = sums + 512;

  // ---- CSR (all 3 layers) co-dispatched with layer-1 GEMM; zeroes bn sums ----
  mega1<<<1120, 256, 0, stream>>>(x0, W0, attS, attD, src0, dst0, Hbuf, es, ed,
                                  csr1, csr2, csr3, rs1, rs2, rs3, cnt1, cnt2, cnt3,
                                  sums);

  // ---- layer 1 aggregate ----
  gat_pool<<<8192, 256, 0, stream>>>(Hbuf, es, ed, csr1, rs1, cnt1, bias, Xbuf, 32768);

  // ---- layer 2 ----
  bn_stats<<<128, 256, 0, stream>>>(Xbuf, sums0, 16384);
  gemm_attn128<<<512, 256, 0, stream>>>(Xbuf, W1, sums0, 1.f / 16384.f,
                                        attS + 128, attD + 128, Hbuf, es, ed);
  gat_pool<<<4096, 256, 0, stream>>>(Hbuf, es, ed, csr2, rs2, cnt2, bias + 128, Xbuf, 16384);

  // ---- layer 3 ----
  bn_stats<<<128, 256, 0, stream>>>(Xbuf, sums1, 8192);
  gemm_attn128<<<256, 256, 0, stream>>>(Xbuf, W2, sums1, 1.f / 8192.f,
                                        attS + 256, attD + 256, Hbuf, es, ed);
  gat_pool<<<2048, 256, 0, stream>>>(Hbuf, es, ed, csr3, rs3, cnt3, bias + 256, Xbuf, 8192);

  // ---- final BN ----
  bn_stats<<<128, 256, 0, stream>>>(Xbuf, sums2, 4096);
  bn_norm<<<2048, 256, 0, stream>>>(Xbuf, sums2, out, 4096);
}

// Round 5
// 203.582 us; speedup vs baseline: 1.3265x; 1.1172x over previous
//
#include <hip/hip_runtime.h>

// Problem constants: B=32 graphs, N=1024 nodes/graph, F=64, D=128, DEG=8
#define E_TOTAL 262144     // B*N*DEG
#define NGRAPH  32
#define EPG     8192       // edges per graph
#define EPS_BN  1e-5f
#define MB (1u << 20)
#define KB (1u << 10)

__device__ __forceinline__ float lrelu(float x){ return x > 0.f ? x : 0.2f * x; }

// XCD-aware block swizzle (locality-neutral measured, harmless).
__device__ __forceinline__ int xcd_swz(int b, int n){ return (b & 7) * (n >> 3) + (b >> 3); }

// exclusive scan of B = 256*Q LDS bins by 256 threads; writes cnt/row_start globals,
// leaves per-bin exclusive cursors in h. Caller must barrier before entry.
template<int Q>
__device__ __forceinline__ void scan_bins(int* h, int* cnt_g, int* rs_g, int B, int g,
                                          int ebase, int* wsum){
  int t = threadIdx.x, lane = t & 63, w = t >> 6;
  int c[Q]; int s = 0;
  #pragma unroll
  for (int i = 0; i < Q; ++i){ c[i] = h[t * Q + i]; s += c[i]; }
  int v = s;
  #pragma unroll
  for (int o = 1; o < 64; o <<= 1){ int u = __shfl_up(v, o); if (lane >= o) v += u; }
  if (lane == 63) wsum[w] = v;
  __syncthreads();
  if (t == 0){ int run = 0;
    #pragma unroll
    for (int i = 0; i < 4; ++i){ int x = wsum[i]; wsum[i] = run; run += x; } }
  __syncthreads();
  int run = v - s + wsum[w];
  #pragma unroll
  for (int i = 0; i < Q; ++i){
    cnt_g[g * B + t * Q + i] = c[i];
    rs_g [g * B + t * Q + i] = ebase + run;
    h[t * Q + i] = run;
    run += c[i];
  }
  __syncthreads();
}

// ---------------- mega1: CSR build (all 3 layers) CO-DISPATCHED with layer-1 GEMM -------
// blocks 0..95: CSR. role 0 (0-31): L1 hist+scan+scatter (no dedupe) + zero the 3 layers'
// BN partial arrays. role 1: L2 pair-dedupe. role 2: L2-redo + L3 dedupe. 256 thr,
// 32 edges/thread. blocks 96..1119: layer-1 GEMM (1024 tiles of 32 rows) + es/ed.
// NOTE (r3 post-mortem): NO in-kernel grid barriers — a device-scope barrier measured
// ~45 us on this chip (cross-XCD arrival serialization + acquire invalidate). Launch
// boundaries are the sync primitive; BN stats flow through 64-bank partial arrays.
__global__ __launch_bounds__(256, 2)
void mega1(const float* __restrict__ x0, const float* __restrict__ W0,
           const float* __restrict__ a_s, const float* __restrict__ a_d,
           const int* __restrict__ src0, const int* __restrict__ dst0,
           float* __restrict__ C, float* __restrict__ es, float* __restrict__ ed,
           int* __restrict__ csr1, int* __restrict__ csr2, int* __restrict__ csr3,
           int* __restrict__ rs1, int* __restrict__ rs2, int* __restrict__ rs3,
           int* __restrict__ cnt1, int* __restrict__ cnt2, int* __restrict__ cnt3,
           float* __restrict__ partials_all){
  __shared__ __align__(16) char smem[45072];   // union: csr 44KB / gemm 41KB
  __shared__ int wsum[4];
  int t = threadIdx.x;
  int raw = blockIdx.x;

  if (raw < 96){
    int* bm2 = (int*)smem;          // [8192] 32 KB
    int* bm3 = bm2 + 8192;          // [2048]  8 KB
    int* h   = bm3 + 2048;          // [1024]  4 KB
    int role = raw >> 5, g = raw & 31, ebase = g * EPG;

    if (role == 0){
      // zero 3 layers x 64 banks x 256 BN partials (49152 floats) across 32 blocks
      for (int i = g * 256 + t; i < 3 * 64 * 256; i += 8192) partials_all[i] = 0.f;
      // ---- L1: no dedupe, 1024 bins ----
      for (int i = t; i < 1024; i += 256) h[i] = 0;
      __syncthreads();
      for (int i = 0; i < 32; ++i){
        int e = ebase + i * 256 + t;
        int sv = src0[e], dv = dst0[e];
        if (sv != dv) atomicAdd(&h[dv & 1023], 1);
      }
      __syncthreads();
      scan_bins<4>(h, cnt1, rs1, 1024, g, ebase, wsum);
      for (int i = 0; i < 32; ++i){
        int e = ebase + i * 256 + t;
        int sv = src0[e], dv = dst0[e];
        if (sv != dv){
          int p = atomicAdd(&h[dv & 1023], 1);
          csr1[ebase + p] = sv;
        }
      }
    } else if (role == 1){
      // ---- L2: pair-dedupe (512x512 bitmap), 512 bins ----
      for (int i = t; i < 8192; i += 256) bm2[i] = 0;
      for (int i = t; i < 512; i += 256) h[i] = 0;
      __syncthreads();
      unsigned int k2m = 0;
      for (int i = 0; i < 32; ++i){
        int e = ebase + i * 256 + t;
        int sv = src0[e], dv = dst0[e];
        if (sv != dv){
          int s2 = (sv >> 1) & 511, d2 = (dv >> 1) & 511;
          if (s2 != d2){
            int key = (s2 << 9) | d2;
            unsigned int bit = 1u << (key & 31);
            unsigned int old = atomicOr((unsigned int*)&bm2[key >> 5], bit);
            if (!(old & bit)){ k2m |= 1u << i; atomicAdd(&h[d2], 1); }
          }
        }
      }
      __syncthreads();
      scan_bins<2>(h, cnt2, rs2, 512, g, ebase, wsum);
      for (int i = 0; i < 32; ++i){
        if ((k2m >> i) & 1u){
          int e = ebase + i * 256 + t;
          int sv = src0[e], dv = dst0[e];
          int p = atomicAdd(&h[(dv >> 1) & 511], 1);
          csr2[ebase + p] = sv >> 1;
        }
      }
    } else {
      // ---- L3: redo L2 dedupe (independent bitmap) then L3 dedupe, 256 bins ----
      for (int i = t; i < 8192; i += 256) bm2[i] = 0;
      for (int i = t; i < 2048; i += 256) bm3[i] = 0;
      for (int i = t; i < 256; i += 256) h[i] = 0;
      __syncthreads();
      unsigned int k3m = 0;
      for (int i = 0; i < 32; ++i){
        int e = ebase + i * 256 + t;
        int sv = src0[e], dv = dst0[e];
        if (sv != dv){
          int s2 = (sv >> 1) & 511, d2 = (dv >> 1) & 511;
          if (s2 != d2){
            int key = (s2 << 9) | d2;
            unsigned int bit = 1u << (key & 31);
            unsigned int old = atomicOr((unsigned int*)&bm2[key >> 5], bit);
            if (!(old & bit)){
              int s3 = (sv >> 2) & 255, d3 = (dv >> 2) & 255;
              if (s3 != d3){
                int key3 = (s3 << 8) | d3;
                unsigned int b3 = 1u << (key3 & 31);
                unsigned int o3 = atomicOr((unsigned int*)&bm3[key3 >> 5], b3);
                if (!(o3 & b3)){ k3m |= 1u << i; atomicAdd(&h[d3], 1); }
              }
            }
          }
        }
      }
      __syncthreads();
      scan_bins<1>(h, cnt3, rs3, 256, g, ebase, wsum);
      for (int i = 0; i < 32; ++i){
        if ((k3m >> i) & 1u){
          int e = ebase + i * 256 + t;
          int sv = src0[e], dv = dst0[e];
          int p = atomicAdd(&h[(dv >> 2) & 255], 1);
          csr3[ebase + p] = sv >> 2;
        }
      }
    }
    return;
  }

  // ---- layer-1 GEMM tile (K=64, no BN) ----
  float* Ws   = (float*)smem;       // [64*128] 32 KB
  float* As_t = Ws + 8192;          // [64*36]   9 KB
  int tile = xcd_swz(raw - 96, 1024);
  int row0 = tile * 32;
  int c2 = t & 63, rg = t >> 6;
  float2 acc[8];
  #pragma unroll
  for (int i = 0; i < 8; ++i){ acc[i].x = 0.f; acc[i].y = 0.f; }

  for (int i = t; i < 8192; i += 256) Ws[i] = W0[i];
  #pragma unroll
  for (int it = 0; it < 8; ++it){
    int i = it * 256 + t;
    int r = i >> 6, kk = i & 63;
    As_t[kk * 36 + r] = x0[(size_t)(row0 + r) * 64 + kk];
  }
  __syncthreads();
  #pragma unroll 8
  for (int kk = 0; kk < 64; ++kk){
    float2 w = *(float2*)&Ws[kk * 128 + c2 * 2];
    float4 a0 = *(float4*)&As_t[kk * 36 + rg * 8];
    float4 a1 = *(float4*)&As_t[kk * 36 + rg * 8 + 4];
    acc[0].x = fmaf(a0.x, w.x, acc[0].x); acc[0].y = fmaf(a0.x, w.y, acc[0].y);
    acc[1].x = fmaf(a0.y, w.x, acc[1].x); acc[1].y = fmaf(a0.y, w.y, acc[1].y);
    acc[2].x = fmaf(a0.z, w.x, acc[2].x); acc[2].y = fmaf(a0.z, w.y, acc[2].y);
    acc[3].x = fmaf(a0.w, w.x, acc[3].x); acc[3].y = fmaf(a0.w, w.y, acc[3].y);
    acc[4].x = fmaf(a1.x, w.x, acc[4].x); acc[4].y = fmaf(a1.x, w.y, acc[4].y);
    acc[5].x = fmaf(a1.y, w.x, acc[5].x); acc[5].y = fmaf(a1.y, w.y, acc[5].y);
    acc[6].x = fmaf(a1.z, w.x, acc[6].x); acc[6].y = fmaf(a1.z, w.y, acc[6].y);
    acc[7].x = fmaf(a1.w, w.x, acc[7].x); acc[7].y = fmaf(a1.w, w.y, acc[7].y);
  }
  float2 as2 = ((const float2*)a_s)[c2];
  float2 ad2 = ((const float2*)a_d)[c2];
  float2* C2 = (float2*)C;
  #pragma unroll
  for (int i = 0; i < 8; ++i){
    int r = row0 + rg * 8 + i;
    C2[(size_t)r * 64 + c2] = acc[i];
    float e1 = acc[i].x * as2.x + acc[i].y * as2.y;
    float e2 = acc[i].x * ad2.x + acc[i].y * ad2.y;
    #pragma unroll
    for (int o = 32; o; o >>= 1){ e1 += __shfl_xor(e1, o); e2 += __shfl_xor(e2, o); }
    if (c2 == 0){ es[r] = e1; ed[r] = e2; }
  }
}

// ---------------- GEMM (K=128) + attention terms; BN stats from 64-bank partials --------
// Prologue reduces partials[64][256] (written by the preceding gat_pool) into mu/rsig.
// The producer->consumer kernel-launch boundary is the only synchronization needed.
__global__ __launch_bounds__(256)
void gemm_attn128(const float* __restrict__ A, const float* __restrict__ W,
                  const float* __restrict__ partials, float invM,
                  const float* __restrict__ a_s, const float* __restrict__ a_d,
                  float* __restrict__ C, float* __restrict__ es, float* __restrict__ ed){
  __shared__ float Ws[64 * 128];    // 32 KB
  __shared__ float As_t[64 * 36];   // 9 KB
  __shared__ float red[256];
  __shared__ float bnmu[128], bnrs[128];
  int t = threadIdx.x;
  {
    float s = 0.f;
    #pragma unroll
    for (int k = 0; k < 64; ++k) s += partials[(k << 8) + t];
    red[t] = s;
  }
  __syncthreads();
  if (t < 128){
    float mu = red[t] * invM;
    float var = red[128 + t] * invM - mu * mu;
    bnmu[t] = mu; bnrs[t] = rsqrtf(var + EPS_BN);
  }
  int bid = xcd_swz(blockIdx.x, gridDim.x);
  int row0 = bid * 32;
  int c2 = t & 63, rg = t >> 6;
  float2 acc[8];
  #pragma unroll
  for (int i = 0; i < 8; ++i){ acc[i].x = 0.f; acc[i].y = 0.f; }

  for (int k0 = 0; k0 < 128; k0 += 64){
    __syncthreads();
    for (int i = t; i < 64 * 128; i += 256)
      Ws[i] = W[(size_t)(k0 + (i >> 7)) * 128 + (i & 127)];
    #pragma unroll
    for (int it = 0; it < 8; ++it){
      int i = it * 256 + t;
      int r = i >> 6, kk = i & 63;
      float v = A[(size_t)(row0 + r) * 128 + k0 + kk];
      v = (v - bnmu[k0 + kk]) * bnrs[k0 + kk];
      As_t[kk * 36 + r] = v;
    }
    __syncthreads();
    #pragma unroll 8
    for (int kk = 0; kk < 64; ++kk){
      float2 w = *(float2*)&Ws[kk * 128 + c2 * 2];
      float4 a0 = *(float4*)&As_t[kk * 36 + rg * 8];
      float4 a1 = *(float4*)&As_t[kk * 36 + rg * 8 + 4];
      acc[0].x = fmaf(a0.x, w.x, acc[0].x); acc[0].y = fmaf(a0.x, w.y, acc[0].y);
      acc[1].x = fmaf(a0.y, w.x, acc[1].x); acc[1].y = fmaf(a0.y, w.y, acc[1].y);
      acc[2].x = fmaf(a0.z, w.x, acc[2].x); acc[2].y = fmaf(a0.z, w.y, acc[2].y);
      acc[3].x = fmaf(a0.w, w.x, acc[3].x); acc[3].y = fmaf(a0.w, w.y, acc[3].y);
      acc[4].x = fmaf(a1.x, w.x, acc[4].x); acc[4].y = fmaf(a1.x, w.y, acc[4].y);
      acc[5].x = fmaf(a1.y, w.x, acc[5].x); acc[5].y = fmaf(a1.y, w.y, acc[5].y);
      acc[6].x = fmaf(a1.z, w.x, acc[6].x); acc[6].y = fmaf(a1.z, w.y, acc[6].y);
      acc[7].x = fmaf(a1.w, w.x, acc[7].x); acc[7].y = fmaf(a1.w, w.y, acc[7].y);
    }
  }
  float2 as2 = ((const float2*)a_s)[c2];
  float2 ad2 = ((const float2*)a_d)[c2];
  float2* C2 = (float2*)C;
  #pragma unroll
  for (int i = 0; i < 8; ++i){
    int r = row0 + rg * 8 + i;
    C2[(size_t)r * 64 + c2] = acc[i];
    float e1 = acc[i].x * as2.x + acc[i].y * as2.y;
    float e2 = acc[i].x * ad2.x + acc[i].y * ad2.y;
    #pragma unroll
    for (int o = 32; o; o >>= 1){ e1 += __shfl_xor(e1, o); e2 += __shfl_xor(e2, o); }
    if (c2 == 0){ es[r] = e1; ed[r] = e2; }
  }
}

// ---------------- GAT softmax-aggregate + bias + ReLU + pairwise max-pool ----------------
// one wave per dst node; block 256 -> nodes 4b..4b+3 = pool pairs; writes M/2 pooled rows.
// Epilogue also accumulates this block's 2 pooled rows into the layer's 64-bank BN
// partial array (sum + sumsq per channel) -> no separate bn_stats dispatch.
__global__ void gat_pool(const float* __restrict__ h, const float* __restrict__ es,
                         const float* __restrict__ ed, const int* __restrict__ csr_src,
                         const int* __restrict__ row_start, const int* __restrict__ row_cnt,
                         const float* __restrict__ bias, float* __restrict__ xout,
                         float* __restrict__ partials, int M){
  __shared__ float2 osh[4][64];
  int lane = threadIdx.x & 63;
  int wave = threadIdx.x >> 6;
  int bid = xcd_swz(blockIdx.x, gridDim.x);
  int n = bid * 4 + wave;
  int start = row_start[n];
  int cnt   = row_cnt[n];
  float edn = ed[n];
  float selfl = lrelu(es[n] + edn);

  float m_l = -1e30f, d_l = 0.f;
  int   s_c = 0; float l_c = 0.f;
  for (int c0 = 0; c0 < cnt; c0 += 64){
    int j = c0 + lane;
    if (j < cnt){
      int s = csr_src[start + j];
      float l = lrelu(es[s] + edn);
      if (c0 == 0){ s_c = s; l_c = l; }
      float mn = fmaxf(m_l, l);
      d_l = d_l * __expf(m_l - mn) + __expf(l - mn);
      m_l = mn;
    }
  }
  #pragma unroll
  for (int o = 32; o; o >>= 1){
    float m2 = __shfl_xor(m_l, o), d2 = __shfl_xor(d_l, o);
    float mn = fmaxf(m_l, m2);
    d_l = d_l * __expf(m_l - mn) + d2 * __expf(m2 - mn);
    m_l = mn;
  }
  float mf  = fmaxf(m_l, selfl);
  float den = d_l * __expf(m_l - mf) + __expf(selfl - mf);

  const float2* h2 = (const float2*)h;
  float sw = __expf(selfl - mf);
  float2 hv = h2[(size_t)n * 64 + lane];
  float2 acc; acc.x = sw * hv.x; acc.y = sw * hv.y;
  for (int c0 = 0; c0 < cnt; c0 += 64){
    int j = c0 + lane;
    int s_j; float w_j;
    if (c0 == 0){
      s_j = s_c;
      w_j = (lane < cnt) ? __expf(l_c - mf) : 0.f;
    } else {
      s_j = 0; w_j = 0.f;
      if (j < cnt){
        s_j = csr_src[start + j];
        w_j = __expf(lrelu(es[s_j] + edn) - mf);
      }
    }
    int rem = min(64, cnt - c0);
    int k = 0;
    for (; k + 8 <= rem; k += 8){
      int ss[8]; float ww[8]; float2 hh[8];
      #pragma unroll
      for (int i = 0; i < 8; ++i){ ss[i] = __shfl(s_j, k + i); ww[i] = __shfl(w_j, k + i); }
      #pragma unroll
      for (int i = 0; i < 8; ++i){ hh[i] = h2[(size_t)ss[i] * 64 + lane]; }
      #pragma unroll
      for (int i = 0; i < 8; ++i){
        acc.x = fmaf(ww[i], hh[i].x, acc.x);
        acc.y = fmaf(ww[i], hh[i].y, acc.y);
      }
    }
    for (; k < rem; ++k){
      int s = __shfl(s_j, k); float w = __shfl(w_j, k);
      float2 hh = h2[(size_t)s * 64 + lane];
      acc.x = fmaf(w, hh.x, acc.x);
      acc.y = fmaf(w, hh.y, acc.y);
    }
  }
  float inv = 1.f / den;
  float2 bv = ((const float2*)bias)[lane];
  float2 o2;
  o2.x = fmaxf(acc.x * inv + bv.x, 0.f);
  o2.y = fmaxf(acc.y * inv + bv.y, 0.f);
  osh[wave][lane] = o2;
  __syncthreads();
  float2 p;
  if (wave < 2){
    float2 a = osh[2 * wave][lane], b = osh[2 * wave + 1][lane];
    p.x = fmaxf(a.x, b.x); p.y = fmaxf(a.y, b.y);
    ((float2*)xout)[(size_t)(bid * 2 + wave) * 64 + lane] = p;
  }
  __syncthreads();
  if (wave < 2) osh[wave][lane] = p;   // pooled rows 0,1
  __syncthreads();
  float* part = partials + ((bid & 63) << 8);
  if (wave == 0){
    float2 a = osh[0][lane], b = osh[1][lane];
    atomicAdd(&part[2 * lane],     a.x + b.x);
    atomicAdd(&part[2 * lane + 1], a.y + b.y);
  } else if (wave == 1){
    float2 a = osh[0][lane], b = osh[1][lane];
    atomicAdd(&part[128 + 2 * lane],     a.x * a.x + b.x * b.x);
    atomicAdd(&part[128 + 2 * lane + 1], a.y * a.y + b.y * b.y);
  }
}

// ---------------- final BatchNorm: reduce partials + normalize, one kernel ---------------
__global__ __launch_bounds__(256)
void bn_norm(const float* __restrict__ in, const float* __restrict__ partials,
             float* __restrict__ out, int M){
  __shared__ float red[256];
  __shared__ float mu_s[128], rs_s[128];
  int t = threadIdx.x;
  {
    float s = 0.f;
    #pragma unroll
    for (int k = 0; k < 64; ++k) s += partials[(k << 8) + t];
    red[t] = s;
  }
  __syncthreads();
  if (t < 128){
    float mu = red[t] / (float)M;
    float var = red[128 + t] / (float)M - mu * mu;
    mu_s[t] = mu; rs_s[t] = rsqrtf(var + EPS_BN);
  }
  __syncthreads();
  int total = M * 128;
  for (int idx = blockIdx.x * 256 + t; idx < total; idx += gridDim.x * 256){
    int c = idx & 127;
    out[idx] = (in[idx] - mu_s[c]) * rs_s[c];
  }
}

extern "C" void kernel_launch(void* const* d_in, const int* in_sizes, int n_in,
                              void* d_out, int out_size, void* d_ws, size_t ws_size,
                              hipStream_t stream){
  const float* x0   = (const float*)d_in[0];
  const float* W0   = (const float*)d_in[1];
  const float* W1   = (const float*)d_in[2];
  const float* W2   = (const float*)d_in[3];
  const float* attS = (const float*)d_in[4];
  const float* attD = (const float*)d_in[5];
  const float* bias = (const float*)d_in[6];
  const int*   src0 = (const int*)d_in[7];
  const int*   dst0 = src0 + E_TOTAL;
  float* out = (float*)d_out;                  // (32, 16384) f32

  char* ws = (char*)d_ws;
  float* Hbuf   = (float*)(ws);                        // 16 MB
  float* Xbuf   = (float*)(ws + 16 * MB);              //  8 MB (pooled)
  int*   csr1   = (int*)  (ws + 24 * MB);              //  1 MB
  int*   csr2   = (int*)  (ws + 25 * MB);              //  1 MB
  int*   csr3   = (int*)  (ws + 26 * MB);              //  1 MB
  float* es     = (float*)(ws + 27 * MB);              // 128 KB
  float* ed     = (float*)(ws + 27 * MB + 128 * KB);   // 128 KB
  int*   rs1    = (int*)  (ws + 27 * MB + 256 * KB);   // 128 KB
  int*   rs2    = (int*)  (ws + 27 * MB + 384 * KB);   //  64 KB
  int*   rs3    = (int*)  (ws + 27 * MB + 448 * KB);   //  32 KB
  int*   cnt1   = (int*)  (ws + 27 * MB + 480 * KB);   // 128 KB
  int*   cnt2   = (int*)  (ws + 27 * MB + 608 * KB);   //  64 KB
  int*   cnt3   = (int*)  (ws + 27 * MB + 672 * KB);   //  32 KB
  float* parts  = (float*)(ws + 27 * MB + 704 * KB);   // 3 x 64 x 256 floats (192 KB)
  float* parts0 = parts, *parts1 = parts + 64 * 256, *parts2 = parts + 2 * 64 * 256;

  // ---- CSR (all 3 layers) co-dispatched with layer-1 GEMM; zeroes BN partials ----
  mega1<<<1120, 256, 0, stream>>>(x0, W0, attS, attD, src0, dst0, Hbuf, es, ed,
                                  csr1, csr2, csr3, rs1, rs2, rs3, cnt1, cnt2, cnt3,
                                  parts);

  // ---- layer 1 aggregate (+ BN partials for layer-2 stats) ----
  gat_pool<<<8192, 256, 0, stream>>>(Hbuf, es, ed, csr1, rs1, cnt1, bias, Xbuf,
                                     parts0, 32768);

  // ---- layer 2 ----
  gemm_attn128<<<512, 256, 0, stream>>>(Xbuf, W1, parts0, 1.f / 16384.f,
                                        attS + 128, attD + 128, Hbuf, es, ed);
  gat_pool<<<4096, 256, 0, stream>>>(Hbuf, es, ed, csr2, rs2, cnt2, bias + 128, Xbuf,
                                     parts1, 16384);

  // ---- layer 3 ----
  gemm_attn128<<<256, 256, 0, stream>>>(Xbuf, W2, parts1, 1.f / 8192.f,
                                        attS + 256, attD + 256, Hbuf, es, ed);
  gat_pool<<<2048, 256, 0, stream>>>(Hbuf, es, ed, csr3, rs3, cnt3, bias + 256, Xbuf,
                                     parts2, 8192);

  // ---- final BN: reduce partials + normalize ----
  bn_norm<<<512, 256, 0, stream>>>(Xbuf, parts2, out, 4096);
}